// Round 13
// baseline (59.219 us; speedup 1.0000x reference)
//
#include <hip/hip_runtime.h>
#include <hip/hip_bf16.h>

typedef __attribute__((ext_vector_type(8))) short bf16x8;
typedef __attribute__((ext_vector_type(4))) float f32x4;
typedef __attribute__((ext_vector_type(4))) unsigned u32x4;

constexpr int L     = 128;
constexpr int BK    = 256;           // f32 columns per chunk (stored bf16 in LDS)
constexpr int GRID  = 256;           // 1 block/CU (128 KB LDS)
constexpr int PITCH = BK * 2;        // 512 B per LDS row

__device__ inline float blo(unsigned w) { unsigned v = w << 16;          return __builtin_bit_cast(float, v); }
__device__ inline float bhi(unsigned w) { unsigned v = w & 0xffff0000u;  return __builtin_bit_cast(float, v); }

__global__ __launch_bounds__(512, 2)
void gram_kernel(const float* __restrict__ slots, uint2* __restrict__ p16,
                 unsigned* __restrict__ cnt, int D, int nChunks, int G) {
    __shared__ __align__(16) char lds[2][L * PITCH];   // 2 x 64 KB
    const int t    = threadIdx.x;        // 0..511
    const int wave = t >> 6;             // 0..7: wave owns rows [16w, 16w+16)
    const int lane = t & 63;

    if (blockIdx.x == 0 && t == 0) *cnt = 0;   // ticket for reduce_finalize

    f32x4 acc[8];
#pragma unroll
    for (int c = 0; c < 8; ++c) acc[c] = (f32x4)0.f;

    u32x4 ld[16];

    // stage 128 rows x 256 f32. One wave-instruction = one row's contiguous 1 KB.
    // NON-TEMPORAL: slots is strictly read-once; bypass L2/L3 allocation.
    auto issue = [&](int chunk) {
#pragma unroll
        for (int q = 0; q < 16; ++q) {
            const int row = wave * 16 + q;
            ld[q] = __builtin_nontemporal_load(reinterpret_cast<const u32x4*>(
                slots + (size_t)row * D + (size_t)chunk * BK + lane * 4));
        }
    };
    // f32 -> bf16 truncation, XOR-swizzled ds_write_b64 (one row per instr,
    // 64 lanes x 8 B = 512 B span = 2-way bank aliasing = free)
    auto commit = [&](int buf) {
#pragma unroll
        for (int q = 0; q < 16; ++q) {
            const int row = wave * 16 + q;
            uint2 w;
            w.x = __builtin_amdgcn_perm(ld[q][1], ld[q][0], 0x07060302u);   // lo=e0 hi=e1
            w.y = __builtin_amdgcn_perm(ld[q][3], ld[q][2], 0x07060302u);   // lo=e2 hi=e3
            int byte = (lane * 8) ^ ((row & 7) << 4);
            *reinterpret_cast<uint2*>(&lds[buf][row * PITCH + byte]) = w;
        }
    };
    // 8 bf16 of row `row`, local k = kk + (lane>>4)*8 .. +7: one ds_read_b128
    auto ldfrag = [&](int buf, int row, int kk) -> bf16x8 {
        int byte = row * PITCH + ((kk * 2 + ((lane >> 4) << 4)) ^ ((row & 7) << 4));
        return *reinterpret_cast<const bf16x8*>(&lds[buf][byte]);
    };

    issue(blockIdx.x);
    commit(0);
    __syncthreads();

    int k = 0;
    for (int c = blockIdx.x; c < nChunks; c += G, ++k) {
        const int cur = k & 1;
        const bool more = (c + G < nChunks);
        if (more) issue(c + G);          // loads overlap the MFMA phase below

#pragma unroll
        for (int kk = 0; kk < BK; kk += 32) {
            bf16x8 a = ldfrag(cur, wave * 16 + (lane & 15), kk);
#pragma unroll
            for (int cc = 0; cc < 8; ++cc) {
                bf16x8 b = ldfrag(cur, cc * 16 + (lane & 15), kk);
                acc[cc] = __builtin_amdgcn_mfma_f32_16x16x32_bf16(a, b, acc[cc], 0, 0, 0);
            }
        }

        if (more) commit(cur ^ 1);       // other buffer; prev barrier made it safe
        __syncthreads();
    }

    // ---- coalesced bf16 partial writeout: uint2 slot j = cc*512 + t ----
    uint2* pb = p16 + (size_t)blockIdx.x * 4096;     // 32 KB per block
#pragma unroll
    for (int cc = 0; cc < 8; ++cc) {
        const unsigned* a = reinterpret_cast<const unsigned*>(&acc[cc]);
        uint2 w;
        w.x = __builtin_amdgcn_perm(a[1], a[0], 0x07060302u);   // lo=reg0 hi=reg1
        w.y = __builtin_amdgcn_perm(a[3], a[2], 0x07060302u);   // lo=reg2 hi=reg3
        pb[cc * 512 + t] = w;
    }
}

// 256 blocks x 256 threads; block owns 16 contiguous uint2-slots (128 B coalesced
// per 16-lane group); 16 sub-groups split the b-range.
// Single-writer gram; last block (ticket) finalizes with LDS-staged gram.
__global__ __launch_bounds__(256)
void reduce_finalize(const uint2* __restrict__ p16, float* __restrict__ gram,
                     unsigned* __restrict__ cnt,
                     const float* __restrict__ temperature, float* __restrict__ out,
                     int G) {
    __shared__ __align__(16) float g[L * L];     // 64 KB (red tree aliases head)
    __shared__ float norms[L];
    __shared__ float wred[4];
    __shared__ unsigned ticket_s;
    const int t   = threadIdx.x;
    const int sl  = t & 15;              // slot within block
    const int sub = t >> 4;              // 0..15: b-range split
    const int j   = blockIdx.x * 16 + sl;        // uint2 slot 0..4095

    f32x4 s = (f32x4)0.f;
#pragma unroll 8
    for (int b = sub; b < G; b += 16) {
        const uint2 u = p16[(size_t)b * 4096 + j];
        s[0] += blo(u.x); s[1] += bhi(u.x);
        s[2] += blo(u.y); s[3] += bhi(u.y);
    }
    f32x4* red = reinterpret_cast<f32x4*>(g);    // [16][16]
    red[sub * 16 + sl] = s;
    __syncthreads();
    if (t < 16) {
        f32x4 s4 = red[t];
#pragma unroll
        for (int w = 1; w < 16; ++w) s4 += red[w * 16 + t];
        const int myj  = blockIdx.x * 16 + t;
        const int cc   = myj >> 9;
        const int tenc = myj & 511;
        const int wv = tenc >> 6, ln = tenc & 63;
        const int growb = wv * 16 + ((ln >> 4) << 2);
        const int gcol  = cc * 16 + (ln & 15);
#pragma unroll
        for (int q = 0; q < 4; ++q) gram[(growb + q) * L + gcol] = s4[q];
    }

    __syncthreads();
    if (t == 0) {
        __threadfence();
        ticket_s = atomicAdd(cnt, 1u);
    }
    __syncthreads();
    if (ticket_s != (unsigned)(gridDim.x - 1)) return;
    __threadfence();

    // ---------------- finalize (last block only) ----------------
#pragma unroll
    for (int q = 0; q < 16; ++q) {       // stage gram -> LDS (4096 float4)
        int i = t + 256 * q;
        *reinterpret_cast<float4*>(&g[i * 4]) =
            *reinterpret_cast<const float4*>(&gram[i * 4]);
    }
    __syncthreads();
    if (t < L) norms[t] = sqrtf(g[t * L + t]);
    __syncthreads();

    const float invT = 1.0f / temperature[0];
    const int r = t >> 1;                // row, 2 threads per row
    const int q = t & 1;
    const float ni = norms[r];

    float ps = 0.f;
    for (int jj = q; jj < L; jj += 2) {
        float sim = g[r * L + jj] / fmaxf(ni * norms[jj], 1e-6f);
        ps += __expf(sim * invT);
    }
    ps += __shfl_xor(ps, 1);
    const float rowsum = ps;

    float tot = 0.f;
    for (int jj = q; jj < L; jj += 2) {
        if (jj > r) {
            float logit = (g[r * L + jj] / fmaxf(ni * norms[jj], 1e-6f)) * invT;
            tot += -(logit - __logf(rowsum - __expf(logit))) * (float)(jj - r);
        }
    }
#pragma unroll
    for (int m = 1; m < 64; m <<= 1) tot += __shfl_xor(tot, m);
    if ((t & 63) == 0) wred[t >> 6] = tot;
    __syncthreads();
    if (t == 0)
        out[0] = (wred[0] + wred[1] + wred[2] + wred[3]) /
                 ((float)(L - 1) * (float)(L - 1) * 0.5f);
}

extern "C" void kernel_launch(void* const* d_in, const int* in_sizes, int n_in,
                              void* d_out, int out_size, void* d_ws, size_t ws_size,
                              hipStream_t stream) {
    const float* slots       = (const float*)d_in[0];
    const float* temperature = (const float*)d_in[1];
    float* out  = (float*)d_out;

    const int D = in_sizes[0] / L;                  // 262144
    const int nChunks = D / BK;                     // 1024
    int G = GRID;
    if (G > nChunks) G = nChunks;

    uint2*    p16  = (uint2*)d_ws;                                 // G*32 KB = 8 MB
    float*    gram = (float*)((char*)d_ws + (size_t)G * 32768);    // 64 KB
    unsigned* cnt  = (unsigned*)((char*)gram + (size_t)L * L * 4);

    gram_kernel<<<G, 512, 0, stream>>>(slots, p16, cnt, D, nChunks, G);
    reduce_finalize<<<256, 256, 0, stream>>>(p16, gram, cnt, temperature, out, G);
}

// Round 14
// 56.034 us; speedup vs baseline: 1.0568x; 1.0568x over previous
//
#include <hip/hip_runtime.h>
#include <hip/hip_bf16.h>

typedef __attribute__((ext_vector_type(8))) short bf16x8;
typedef __attribute__((ext_vector_type(4))) float f32x4;

constexpr int L     = 128;
constexpr int BK    = 256;           // f32 columns per chunk (stored bf16 in LDS)
constexpr int GRID  = 256;           // 1 block/CU (128 KB LDS)
constexpr int PITCH = BK * 2;        // 512 B per LDS row

__device__ inline float blo(unsigned w) { unsigned v = w << 16;          return __builtin_bit_cast(float, v); }
__device__ inline float bhi(unsigned w) { unsigned v = w & 0xffff0000u;  return __builtin_bit_cast(float, v); }

__global__ __launch_bounds__(512, 2)
void gram_kernel(const float* __restrict__ slots, uint2* __restrict__ p16,
                 unsigned* __restrict__ cnt, int D, int nChunks, int G) {
    __shared__ __align__(16) char lds[2][L * PITCH];   // 2 x 64 KB
    const int t    = threadIdx.x;        // 0..511
    const int wave = t >> 6;             // 0..7: wave owns rows [16w, 16w+16)
    const int lane = t & 63;

    if (blockIdx.x == 0 && t == 0) *cnt = 0;   // ticket for reduce_finalize

    f32x4 acc[8];
#pragma unroll
    for (int c = 0; c < 8; ++c) acc[c] = (f32x4)0.f;

    float4 ld[16];

    // stage 128 rows x 256 f32. Each wave-instruction reads ONE row's contiguous
    // 1 KB (64 lanes x 16 B) -> single DRAM page activation per instruction.
    auto issue = [&](int chunk) {
#pragma unroll
        for (int q = 0; q < 16; ++q) {
            const int row = wave * 16 + q;
            ld[q] = *reinterpret_cast<const float4*>(
                slots + (size_t)row * D + (size_t)chunk * BK + lane * 4);
        }
    };
    // f32 -> bf16 truncation, XOR-swizzled ds_write_b64 (one row per instr,
    // 64 lanes x 8 B = 512 B span = 2-way bank aliasing = free)
    auto commit = [&](int buf) {
#pragma unroll
        for (int q = 0; q < 16; ++q) {
            const int row = wave * 16 + q;
            const unsigned* f = reinterpret_cast<const unsigned*>(&ld[q]);
            uint2 w;
            w.x = __builtin_amdgcn_perm(f[1], f[0], 0x07060302u);   // lo=e0 hi=e1
            w.y = __builtin_amdgcn_perm(f[3], f[2], 0x07060302u);   // lo=e2 hi=e3
            int byte = (lane * 8) ^ ((row & 7) << 4);
            *reinterpret_cast<uint2*>(&lds[buf][row * PITCH + byte]) = w;
        }
    };
    // 8 bf16 of row `row`, local k = kk + (lane>>4)*8 .. +7: one ds_read_b128
    auto ldfrag = [&](int buf, int row, int kk) -> bf16x8 {
        int byte = row * PITCH + ((kk * 2 + ((lane >> 4) << 4)) ^ ((row & 7) << 4));
        return *reinterpret_cast<const bf16x8*>(&lds[buf][byte]);
    };

    issue(blockIdx.x);
    commit(0);
    __syncthreads();

    int k = 0;
    for (int c = blockIdx.x; c < nChunks; c += G, ++k) {
        const int cur = k & 1;
        const bool more = (c + G < nChunks);
        if (more) issue(c + G);          // loads overlap the MFMA phase below

#pragma unroll
        for (int kk = 0; kk < BK; kk += 32) {
            bf16x8 a = ldfrag(cur, wave * 16 + (lane & 15), kk);
#pragma unroll
            for (int cc = 0; cc < 8; ++cc) {
                bf16x8 b = ldfrag(cur, cc * 16 + (lane & 15), kk);
                acc[cc] = __builtin_amdgcn_mfma_f32_16x16x32_bf16(a, b, acc[cc], 0, 0, 0);
            }
        }

        if (more) commit(cur ^ 1);       // other buffer; prev barrier made it safe
        __syncthreads();
    }

    // ---- coalesced bf16 partial writeout: uint2 slot j = cc*512 + t ----
    uint2* pb = p16 + (size_t)blockIdx.x * 4096;     // 32 KB per block
#pragma unroll
    for (int cc = 0; cc < 8; ++cc) {
        const unsigned* a = reinterpret_cast<const unsigned*>(&acc[cc]);
        uint2 w;
        w.x = __builtin_amdgcn_perm(a[1], a[0], 0x07060302u);   // lo=reg0 hi=reg1
        w.y = __builtin_amdgcn_perm(a[3], a[2], 0x07060302u);   // lo=reg2 hi=reg3
        pb[cc * 512 + t] = w;
    }
}

// 256 blocks x 256 threads; block owns 16 contiguous uint2-slots (128 B coalesced
// per 16-lane group); 16 sub-groups split the b-range.
// Single-writer gram; last block (ticket) finalizes with LDS-staged gram.
__global__ __launch_bounds__(256)
void reduce_finalize(const uint2* __restrict__ p16, float* __restrict__ gram,
                     unsigned* __restrict__ cnt,
                     const float* __restrict__ temperature, float* __restrict__ out,
                     int G) {
    __shared__ __align__(16) float g[L * L];     // 64 KB (red tree aliases head)
    __shared__ float norms[L];
    __shared__ float wred[4];
    __shared__ unsigned ticket_s;
    const int t   = threadIdx.x;
    const int sl  = t & 15;              // slot within block
    const int sub = t >> 4;              // 0..15: b-range split
    const int j   = blockIdx.x * 16 + sl;        // uint2 slot 0..4095

    f32x4 s = (f32x4)0.f;
#pragma unroll 8
    for (int b = sub; b < G; b += 16) {
        const uint2 u = p16[(size_t)b * 4096 + j];
        s[0] += blo(u.x); s[1] += bhi(u.x);
        s[2] += blo(u.y); s[3] += bhi(u.y);
    }
    f32x4* red = reinterpret_cast<f32x4*>(g);    // [16][16]
    red[sub * 16 + sl] = s;
    __syncthreads();
    if (t < 16) {
        f32x4 s4 = red[t];
#pragma unroll
        for (int w = 1; w < 16; ++w) s4 += red[w * 16 + t];
        const int myj  = blockIdx.x * 16 + t;
        const int cc   = myj >> 9;
        const int tenc = myj & 511;
        const int wv = tenc >> 6, ln = tenc & 63;
        const int growb = wv * 16 + ((ln >> 4) << 2);
        const int gcol  = cc * 16 + (ln & 15);
#pragma unroll
        for (int q = 0; q < 4; ++q) gram[(growb + q) * L + gcol] = s4[q];
    }

    __syncthreads();
    if (t == 0) {
        __threadfence();
        ticket_s = atomicAdd(cnt, 1u);
    }
    __syncthreads();
    if (ticket_s != (unsigned)(gridDim.x - 1)) return;
    __threadfence();

    // ---------------- finalize (last block only) ----------------
#pragma unroll
    for (int q = 0; q < 16; ++q) {       // stage gram -> LDS (4096 float4)
        int i = t + 256 * q;
        *reinterpret_cast<float4*>(&g[i * 4]) =
            *reinterpret_cast<const float4*>(&gram[i * 4]);
    }
    __syncthreads();
    if (t < L) norms[t] = sqrtf(g[t * L + t]);
    __syncthreads();

    const float invT = 1.0f / temperature[0];
    const int r = t >> 1;                // row, 2 threads per row
    const int q = t & 1;
    const float ni = norms[r];

    float ps = 0.f;
    for (int jj = q; jj < L; jj += 2) {
        float sim = g[r * L + jj] / fmaxf(ni * norms[jj], 1e-6f);
        ps += __expf(sim * invT);
    }
    ps += __shfl_xor(ps, 1);
    const float rowsum = ps;

    float tot = 0.f;
    for (int jj = q; jj < L; jj += 2) {
        if (jj > r) {
            float logit = (g[r * L + jj] / fmaxf(ni * norms[jj], 1e-6f)) * invT;
            tot += -(logit - __logf(rowsum - __expf(logit))) * (float)(jj - r);
        }
    }
#pragma unroll
    for (int m = 1; m < 64; m <<= 1) tot += __shfl_xor(tot, m);
    if ((t & 63) == 0) wred[t >> 6] = tot;
    __syncthreads();
    if (t == 0)
        out[0] = (wred[0] + wred[1] + wred[2] + wred[3]) /
                 ((float)(L - 1) * (float)(L - 1) * 0.5f);
}

extern "C" void kernel_launch(void* const* d_in, const int* in_sizes, int n_in,
                              void* d_out, int out_size, void* d_ws, size_t ws_size,
                              hipStream_t stream) {
    const float* slots       = (const float*)d_in[0];
    const float* temperature = (const float*)d_in[1];
    float* out  = (float*)d_out;

    const int D = in_sizes[0] / L;                  // 262144
    const int nChunks = D / BK;                     // 1024
    int G = GRID;
    if (G > nChunks) G = nChunks;

    uint2*    p16  = (uint2*)d_ws;                                 // G*32 KB = 8 MB
    float*    gram = (float*)((char*)d_ws + (size_t)G * 32768);    // 64 KB
    unsigned* cnt  = (unsigned*)((char*)gram + (size_t)L * L * 4);

    gram_kernel<<<G, 512, 0, stream>>>(slots, p16, cnt, D, nChunks, G);
    reduce_finalize<<<256, 256, 0, stream>>>(p16, gram, cnt, temperature, out, G);
}